// Round 2
// baseline (462.378 us; speedup 1.0000x reference)
//
#include <hip/hip_runtime.h>

// ---------------------------------------------------------------------------
// AttentionBlock (RMSNorm -> gated windowed attention -> RMSNorm -> SwiGLU FFN)
// MI355X / gfx950. bf16 MFMA (16x16x32) everywhere, fp32 accumulate.
// R2: split-K + atomicAdd for occupancy-starved N=1024 GEMMs (wo, out-proj),
//     qkv+gate merged into one N=4096 GEMM, XCD-aware block swizzle (T1),
//     single fused weight-convert kernel.
// ---------------------------------------------------------------------------

#define DEV __device__ __forceinline__

using u16 = unsigned short;
typedef __attribute__((ext_vector_type(8))) short  short8;   // 8 x bf16 (4 VGPR)
typedef __attribute__((ext_vector_type(4))) float  floatx4;

DEV u16 f2bf(float f) {                 // round-to-nearest-even fp32 -> bf16
  unsigned u = __builtin_bit_cast(unsigned, f);
  u += 0x7FFFu + ((u >> 16) & 1u);
  return (u16)(u >> 16);
}
DEV float bf2f(u16 h) {
  unsigned u = ((unsigned)h) << 16;
  return __builtin_bit_cast(float, u);
}
DEV floatx4 mfma16(short8 a, short8 b, floatx4 c) {
  return __builtin_amdgcn_mfma_f32_16x16x32_bf16(a, b, c, 0, 0, 0);
}
DEV void gload16(const u16* g, u16* lds_base_wave_uniform) {
  __builtin_amdgcn_global_load_lds(
      (const __attribute__((address_space(1))) void*)g,
      (__attribute__((address_space(3))) void*)lds_base_wave_uniform,
      16, 0, 0);
}

// ---------------------------------------------------------------------------
// Fused fp32 -> bf16 weight conversion for all 6 weight tensors (one launch).
// Block ranges (256 float4 per block): qkv 3072 | gate 1024 | out 1024 |
// wg 4096 | wu 4096 | wo 4096  => 17408 blocks total.
// ---------------------------------------------------------------------------
__global__ __launch_bounds__(256) void cvt_all_k(
    const float* __restrict__ s0, const float* __restrict__ s1,
    const float* __restrict__ s2, const float* __restrict__ s3,
    const float* __restrict__ s4, const float* __restrict__ s5,
    u16* __restrict__ d0, u16* __restrict__ d1, u16* __restrict__ d2,
    u16* __restrict__ d3, u16* __restrict__ d4, u16* __restrict__ d5) {
  const int b = blockIdx.x;
  const float* in; u16* out; int base;
  if (b < 3072)       { in = s0; out = d0; base = 0; }
  else if (b < 4096)  { in = s1; out = d1; base = 3072; }
  else if (b < 5120)  { in = s2; out = d2; base = 4096; }
  else if (b < 9216)  { in = s3; out = d3; base = 5120; }
  else if (b < 13312) { in = s4; out = d4; base = 9216; }
  else                { in = s5; out = d5; base = 13312; }
  const size_t i = (size_t)(b - base) * 256 + threadIdx.x;
  const float4 v = ((const float4*)in)[i];
  ushort4 r;
  r.x = f2bf(v.x); r.y = f2bf(v.y); r.z = f2bf(v.z); r.w = f2bf(v.w);
  ((ushort4*)out)[i] = r;
}

// ---------------------------------------------------------------------------
// RMSNorm: one block per row (1024 cols), fp32 in -> bf16 out
// ---------------------------------------------------------------------------
__global__ __launch_bounds__(256) void rmsnorm_k(const float* __restrict__ x,
                                                 const float* __restrict__ wt,
                                                 u16* __restrict__ o) {
  __shared__ float red[4];
  const int row = blockIdx.x;
  const int tid = threadIdx.x;
  const float4 v = ((const float4*)(x + (size_t)row * 1024))[tid];
  float ss = v.x * v.x + v.y * v.y + v.z * v.z + v.w * v.w;
  ss += __shfl_xor(ss, 1, 64);
  ss += __shfl_xor(ss, 2, 64);
  ss += __shfl_xor(ss, 4, 64);
  ss += __shfl_xor(ss, 8, 64);
  ss += __shfl_xor(ss, 16, 64);
  ss += __shfl_xor(ss, 32, 64);
  if ((tid & 63) == 0) red[tid >> 6] = ss;
  __syncthreads();
  const float tot = red[0] + red[1] + red[2] + red[3];
  const float sc = rsqrtf(tot * (1.0f / 1024.0f) + 1e-6f);
  const float4 wv = ((const float4*)wt)[tid];
  ushort4 r;
  r.x = f2bf(v.x * sc * wv.x);
  r.y = f2bf(v.y * sc * wv.y);
  r.z = f2bf(v.z * sc * wv.z);
  r.w = f2bf(v.w * sc * wv.w);
  ((ushort4*)(o + (size_t)row * 1024))[tid] = r;
}

// ---------------------------------------------------------------------------
// GEMM: C[M,N] = A[M,K_all] @ B[N,K_all]^T  restricted to K range
// [blockIdx.z*ksz, +ksz).  128x128 tile, BK=32, 4 waves, double-buffered LDS
// via global_load_lds width 16.  T1 XCD swizzle on the flattened block id
// (requires gridDim.x*gridDim.y % 8 == 0 -- true for all launches here).
// Epilogues:
//   2: cb[idx] = silu(v)                 (N-wide bf16)
//   3: cb[idx] = v * aux[idx]            (N-wide bf16, aux bf16)
//   5: atomicAdd(&cf[idx], v)            (fp32, split-K accumulate)
//   6: col<3072 -> cb[row*3072+col]=v ; else cb2[row*1024+col-3072]=sigmoid(v)
// ---------------------------------------------------------------------------
template <int EPI>
__global__ __launch_bounds__(256) void gemm_bf16_k(
    const u16* __restrict__ A, const u16* __restrict__ B, int N, int K,
    int ksz, u16* __restrict__ cb, float* __restrict__ cf,
    const u16* __restrict__ aux, u16* __restrict__ cb2) {
  __shared__ __align__(16) u16 As[2][4096];   // 128 rows x 32 cols
  __shared__ __align__(16) u16 Bs[2][4096];

  const int tid = threadIdx.x;
  const int w = tid >> 6, lane = tid & 63;
  const int wm = w >> 1, wn = w & 1;
  const int g = lane >> 4, r16 = lane & 15;

  // T1: XCD-aware bijective swizzle of the flattened block id
  int bid = blockIdx.y * gridDim.x + blockIdx.x;
  const int cpx = (gridDim.x * gridDim.y) >> 3;
  bid = (bid & 7) * cpx + (bid >> 3);
  const int m0 = (bid / gridDim.x) * 128;
  const int n0 = (bid % gridDim.x) * 128;

  const int kbeg = blockIdx.z * ksz;

  const int crow = lane >> 2;        // row within a 16-row staging chunk
  const int ccol = (lane & 3) * 8;   // element col within 32

  floatx4 acc[4][4];
#pragma unroll
  for (int i = 0; i < 4; i++)
#pragma unroll
    for (int j = 0; j < 4; j++) acc[i][j] = (floatx4){0.f, 0.f, 0.f, 0.f};

  const int nk = ksz >> 5;

  auto stage = [&](int buf, int k0) {
#pragma unroll
    for (int p = 0; p < 2; p++) {
      const int c = p * 4 + w;  // 8 chunks of 16 rows, 2 per wave
      gload16(A + (size_t)(m0 + c * 16 + crow) * K + k0 + ccol, &As[buf][c * 512]);
      gload16(B + (size_t)(n0 + c * 16 + crow) * K + k0 + ccol, &Bs[buf][c * 512]);
    }
  };

  stage(0, kbeg);
  __syncthreads();

  for (int kt = 0; kt < nk; ++kt) {
    const int buf = kt & 1;
    if (kt + 1 < nk) stage(buf ^ 1, kbeg + (kt + 1) * 32);
    short8 af[4], bfr[4];
#pragma unroll
    for (int i = 0; i < 4; i++)
      af[i] = *(const short8*)&As[buf][(wm * 64 + i * 16 + r16) * 32 + g * 8];
#pragma unroll
    for (int j = 0; j < 4; j++)
      bfr[j] = *(const short8*)&Bs[buf][(wn * 64 + j * 16 + r16) * 32 + g * 8];
#pragma unroll
    for (int i = 0; i < 4; i++)
#pragma unroll
      for (int j = 0; j < 4; j++) acc[i][j] = mfma16(af[i], bfr[j], acc[i][j]);
    __syncthreads();
  }

#pragma unroll
  for (int i = 0; i < 4; i++) {
    const int row = m0 + wm * 64 + i * 16 + g * 4;
#pragma unroll
    for (int j = 0; j < 4; j++) {
      const int col = n0 + wn * 64 + j * 16 + r16;
#pragma unroll
      for (int rr = 0; rr < 4; rr++) {
        const float v = acc[i][j][rr];
        if constexpr (EPI == 2) {
          cb[(size_t)(row + rr) * N + col] = f2bf(v / (1.0f + __expf(-v)));
        } else if constexpr (EPI == 3) {
          const size_t idx = (size_t)(row + rr) * N + col;
          cb[idx] = f2bf(v * bf2f(aux[idx]));
        } else if constexpr (EPI == 5) {
          atomicAdd(&cf[(size_t)(row + rr) * N + col], v);
        } else if constexpr (EPI == 6) {
          if (col < 3072)
            cb[(size_t)(row + rr) * 3072 + col] = f2bf(v);
          else
            cb2[(size_t)(row + rr) * 1024 + (col - 3072)] =
                f2bf(1.0f / (1.0f + __expf(-v)));
        }
      }
    }
  }
}

// ---------------------------------------------------------------------------
// Sliding-window causal attention (WINDOW=256) + fused sigmoid-gate multiply.
// (unchanged from R1 — validated)
// ---------------------------------------------------------------------------
__global__ __launch_bounds__(256) void attn_win_kernel(
    const u16* __restrict__ qkv, const u16* __restrict__ gate,
    u16* __restrict__ out) {
  __shared__ __align__(16) u16 Kl[64][80];
  __shared__ __align__(16) u16 Vt[64][80];
  __shared__ __align__(16) u16 Pl[4][16][80];

  const int tid = threadIdx.x;
  const int w = tid >> 6, lane = tid & 63;
  const int g = lane >> 4, r16 = lane & 15;

  const int q0 = blockIdx.x * 64;
  const int h = blockIdx.y;
  const int b = blockIdx.z;
  const u16* qb_ = qkv + (size_t)b * 2048 * 3072;

  const int tq = q0 + w * 16 + r16;
  const u16* qptr = qb_ + (size_t)tq * 3072 + h * 64;
  const short8 aq0 = *(const short8*)(qptr + g * 8);
  const short8 aq1 = *(const short8*)(qptr + 32 + g * 8);

  floatx4 O[4] = {{0,0,0,0},{0,0,0,0},{0,0,0,0},{0,0,0,0}};
  float mrow[4] = {-1e30f, -1e30f, -1e30f, -1e30f};
  float lrow[4] = {0.f, 0.f, 0.f, 0.f};

  const int srow = tid >> 2;
  const int sq4 = tid & 3;
  const int qw = q0 + w * 16;

  for (int kt = q0 - 256; kt <= q0; kt += 64) {
    if (kt < 0) continue;
    {  // ---- stage K and V^T ----
      const u16* kb = qb_ + (size_t)(kt + srow) * 3072 + 1024 + h * 64 + sq4 * 16;
      const short8 kv0 = *(const short8*)kb;
      const short8 kv1 = *(const short8*)(kb + 8);
      *(short8*)&Kl[srow][sq4 * 16] = kv0;
      *(short8*)&Kl[srow][sq4 * 16 + 8] = kv1;
      const u16* vb = kb + 1024;
      const short8 vv0 = *(const short8*)vb;
      const short8 vv1 = *(const short8*)(vb + 8);
#pragma unroll
      for (int j = 0; j < 8; j++) Vt[sq4 * 16 + j][srow] = (u16)vv0[j];
#pragma unroll
      for (int j = 0; j < 8; j++) Vt[sq4 * 16 + 8 + j][srow] = (u16)vv1[j];
    }
    __syncthreads();

    const bool active = (qw + 15 >= kt) && (qw - kt < 319);
    if (active) {
      floatx4 S[4];
#pragma unroll
      for (int nf = 0; nf < 4; nf++) {
        const short8 bk0 = *(const short8*)&Kl[nf * 16 + r16][g * 8];
        const short8 bk1 = *(const short8*)&Kl[nf * 16 + r16][32 + g * 8];
        floatx4 a = {0.f, 0.f, 0.f, 0.f};
        a = mfma16(aq0, bk0, a);
        a = mfma16(aq1, bk1, a);
        S[nf] = a;
      }
      float pm[4][4];
      float nmax[4] = {-1e30f, -1e30f, -1e30f, -1e30f};
#pragma unroll
      for (int nf = 0; nf < 4; nf++) {
        const int key = kt + nf * 16 + r16;
#pragma unroll
        for (int rr = 0; rr < 4; rr++) {
          const int q = qw + g * 4 + rr;
          const int dist = q - key;
          const float s = (dist >= 0 && dist < 256) ? S[nf][rr] : -1e30f;
          pm[nf][rr] = s;
          nmax[rr] = fmaxf(nmax[rr], s);
        }
      }
#pragma unroll
      for (int rr = 0; rr < 4; rr++) {
        float v = nmax[rr];
        v = fmaxf(v, __shfl_xor(v, 1, 64));
        v = fmaxf(v, __shfl_xor(v, 2, 64));
        v = fmaxf(v, __shfl_xor(v, 4, 64));
        v = fmaxf(v, __shfl_xor(v, 8, 64));
        const float mnew = fmaxf(mrow[rr], v);
        const float alpha = __expf(0.125f * (mrow[rr] - mnew));
        mrow[rr] = mnew;
        lrow[rr] *= alpha;
#pragma unroll
        for (int n = 0; n < 4; n++) O[n][rr] *= alpha;
        float ls = 0.f;
#pragma unroll
        for (int nf = 0; nf < 4; nf++) {
          const float s = pm[nf][rr];
          const float pv = (s < -1e29f) ? 0.f : __expf(0.125f * (s - mnew));
          pm[nf][rr] = pv;
          ls += pv;
        }
        ls += __shfl_xor(ls, 1, 64);
        ls += __shfl_xor(ls, 2, 64);
        ls += __shfl_xor(ls, 4, 64);
        ls += __shfl_xor(ls, 8, 64);
        lrow[rr] += ls;
      }
#pragma unroll
      for (int nf = 0; nf < 4; nf++)
#pragma unroll
        for (int rr = 0; rr < 4; rr++)
          Pl[w][g * 4 + rr][nf * 16 + r16] = f2bf(pm[nf][rr]);
#pragma unroll
      for (int kf = 0; kf < 2; kf++) {
        const short8 pa = *(const short8*)&Pl[w][r16][kf * 32 + g * 8];
#pragma unroll
        for (int n = 0; n < 4; n++) {
          const short8 vb8 = *(const short8*)&Vt[n * 16 + r16][kf * 32 + g * 8];
          O[n] = mfma16(pa, vb8, O[n]);
        }
      }
    }
    __syncthreads();
  }

#pragma unroll
  for (int n = 0; n < 4; n++) {
#pragma unroll
    for (int rr = 0; rr < 4; rr++) {
      const int t = qw + g * 4 + rr;
      const size_t idx = ((size_t)(b * 2048 + t)) * 1024 + h * 64 + n * 16 + r16;
      const float gv = bf2f(gate[idx]);
      const float ov = (O[n][rr] / lrow[rr]) * gv;
      out[idx] = f2bf(ov);
    }
  }
}

// ---------------------------------------------------------------------------
// Orchestration.
// ---------------------------------------------------------------------------
extern "C" void kernel_launch(void* const* d_in, const int* in_sizes, int n_in,
                              void* d_out, int out_size, void* d_ws,
                              size_t ws_size, hipStream_t stream) {
  (void)in_sizes; (void)n_in; (void)out_size; (void)ws_size;
  const float* x     = (const float*)d_in[0];
  const float* ln1   = (const float*)d_in[1];
  const float* qkvw  = (const float*)d_in[2];
  const float* gatew = (const float*)d_in[3];
  const float* outw  = (const float*)d_in[4];
  const float* ln2   = (const float*)d_in[5];
  const float* wg    = (const float*)d_in[6];
  const float* wu    = (const float*)d_in[7];
  const float* wo    = (const float*)d_in[8];
  float* outp = (float*)d_out;

  u16* p = (u16*)d_ws;
  u16* qkvw_b  = p; p += 3 * 1024 * 1024;   // must stay adjacent to gatew_b
  u16* gatew_b = p; p += 1024 * 1024;       // (merged N=4096 B operand)
  u16* outw_b  = p; p += 1024 * 1024;
  u16* wg_b    = p; p += 4 * 1024 * 1024;
  u16* wu_b    = p; p += 4 * 1024 * 1024;
  u16* wo_b    = p; p += 4 * 1024 * 1024;
  u16* xn      = p; p += 4096 * 1024;
  u16* qkvb    = p; p += (size_t)4096 * 3072;
  u16* gates   = p; p += 4096 * 1024;
  u16* a3      = p; p += 4096 * 1024;
  u16* hb      = p; p += 4096 * 1024;
  u16* gs      = p; p += (size_t)4096 * 4096;
  float* x2    = (float*)p;

  // all weight conversions in one launch
  cvt_all_k<<<17408, 256, 0, stream>>>(qkvw, gatew, outw, wg, wu, wo,
                                       qkvw_b, gatew_b, outw_b, wg_b, wu_b, wo_b);

  // x_n = rmsnorm(x, ln1) -> bf16
  rmsnorm_k<<<4096, 256, 0, stream>>>(x, ln1, xn);

  // merged: qkv = x_n @ qkv_w.T ; gates = sigmoid(x_n @ gate_w.T)
  // B rows 0..3071 = qkv_w, 3072..4095 = gate_w (contiguous in ws)
  gemm_bf16_k<6><<<dim3(32, 32, 1), 256, 0, stream>>>(
      xn, qkvw_b, 4096, 1024, 1024, qkvb, nullptr, nullptr, gates);

  // a3 = attention(q,k,v) * gates  (bf16)
  attn_win_kernel<<<dim3(32, 16, 2), 256, 0, stream>>>(qkvb, gates, a3);

  // x2 = x + a3 @ out_w.T : seed x2 with x, then split-K=2 atomic GEMM
  hipMemcpyAsync(x2, x, (size_t)4096 * 1024 * 4, hipMemcpyDeviceToDevice, stream);
  gemm_bf16_k<5><<<dim3(8, 32, 2), 256, 0, stream>>>(
      a3, outw_b, 1024, 1024, 512, nullptr, x2, nullptr, nullptr);

  // h = rmsnorm(x2, ln2) -> bf16
  rmsnorm_k<<<4096, 256, 0, stream>>>(x2, ln2, hb);

  // gs = silu(h @ wg.T); gs = gs * (h @ wu.T)
  gemm_bf16_k<2><<<dim3(32, 32, 1), 256, 0, stream>>>(
      hb, wg_b, 4096, 1024, 1024, gs, nullptr, nullptr, nullptr);
  gemm_bf16_k<3><<<dim3(32, 32, 1), 256, 0, stream>>>(
      hb, wu_b, 4096, 1024, 1024, gs, nullptr, gs, nullptr);

  // out = x2 + gs @ wo.T : seed out with x2, then split-K=4 atomic GEMM
  hipMemcpyAsync(outp, x2, (size_t)4096 * 1024 * 4, hipMemcpyDeviceToDevice, stream);
  gemm_bf16_k<5><<<dim3(8, 32, 4), 256, 0, stream>>>(
      gs, wo_b, 1024, 4096, 1024, nullptr, outp, nullptr, nullptr);
}

// Round 3
// 389.039 us; speedup vs baseline: 1.1885x; 1.1885x over previous
//
#include <hip/hip_runtime.h>

// ---------------------------------------------------------------------------
// AttentionBlock (RMSNorm -> gated windowed attention -> RMSNorm -> SwiGLU FFN)
// MI355X / gfx950.  R3: new 8-wave GEMM engine with counted-vmcnt 4-deep
// pipeline (T3+T4), swizzled LDS (T2), setprio MFMA clusters (T5), raw
// s_barrier. No atomics, no d2d memcpys; residuals fused in epilogues.
// ---------------------------------------------------------------------------

#define DEV __device__ __forceinline__

using u16 = unsigned short;
typedef __attribute__((ext_vector_type(8))) short  short8;   // 8 x bf16
typedef __attribute__((ext_vector_type(4))) float  floatx4;

DEV u16 f2bf(float f) {
  unsigned u = __builtin_bit_cast(unsigned, f);
  u += 0x7FFFu + ((u >> 16) & 1u);
  return (u16)(u >> 16);
}
DEV float bf2f(u16 h) {
  unsigned u = ((unsigned)h) << 16;
  return __builtin_bit_cast(float, u);
}
DEV floatx4 mfma16(short8 a, short8 b, floatx4 c) {
  return __builtin_amdgcn_mfma_f32_16x16x32_bf16(a, b, c, 0, 0, 0);
}
DEV void gload16(const u16* g, const u16* lds_base_wave_uniform) {
  __builtin_amdgcn_global_load_lds(
      (const __attribute__((address_space(1))) void*)g,
      (__attribute__((address_space(3))) void*)lds_base_wave_uniform,
      16, 0, 0);
}
// counted vmem waits (T4) — literal immediates, memory clobber so the
// compiler cannot sink LDS reads above them
#define WAITVM(n) asm volatile("s_waitcnt vmcnt(" #n ")" ::: "memory")
DEV void blockbar() {            // raw barrier: does NOT drain vmcnt (T3 core)
  __builtin_amdgcn_sched_barrier(0);
  asm volatile("" ::: "memory");
  __builtin_amdgcn_s_barrier();
  asm volatile("" ::: "memory");
  __builtin_amdgcn_sched_barrier(0);
}

// ---------------------------------------------------------------------------
// Fused fp32 -> bf16 weight conversion (one launch, 17408 blocks)
// ---------------------------------------------------------------------------
__global__ __launch_bounds__(256) void cvt_all_k(
    const float* __restrict__ s0, const float* __restrict__ s1,
    const float* __restrict__ s2, const float* __restrict__ s3,
    const float* __restrict__ s4, const float* __restrict__ s5,
    u16* __restrict__ d0, u16* __restrict__ d1, u16* __restrict__ d2,
    u16* __restrict__ d3, u16* __restrict__ d4, u16* __restrict__ d5) {
  const int b = blockIdx.x;
  const float* in; u16* out; int base;
  if (b < 3072)       { in = s0; out = d0; base = 0; }
  else if (b < 4096)  { in = s1; out = d1; base = 3072; }
  else if (b < 5120)  { in = s2; out = d2; base = 4096; }
  else if (b < 9216)  { in = s3; out = d3; base = 5120; }
  else if (b < 13312) { in = s4; out = d4; base = 9216; }
  else                { in = s5; out = d5; base = 13312; }
  const size_t i = (size_t)(b - base) * 256 + threadIdx.x;
  const float4 v = ((const float4*)in)[i];
  ushort4 r;
  r.x = f2bf(v.x); r.y = f2bf(v.y); r.z = f2bf(v.z); r.w = f2bf(v.w);
  ((ushort4*)out)[i] = r;
}

// ---------------------------------------------------------------------------
// RMSNorm: one block per row (1024 cols), fp32 in -> bf16 out
// ---------------------------------------------------------------------------
__global__ __launch_bounds__(256) void rmsnorm_k(const float* __restrict__ x,
                                                 const float* __restrict__ wt,
                                                 u16* __restrict__ o) {
  __shared__ float red[4];
  const int row = blockIdx.x;
  const int tid = threadIdx.x;
  const float4 v = ((const float4*)(x + (size_t)row * 1024))[tid];
  float ss = v.x * v.x + v.y * v.y + v.z * v.z + v.w * v.w;
  ss += __shfl_xor(ss, 1, 64);
  ss += __shfl_xor(ss, 2, 64);
  ss += __shfl_xor(ss, 4, 64);
  ss += __shfl_xor(ss, 8, 64);
  ss += __shfl_xor(ss, 16, 64);
  ss += __shfl_xor(ss, 32, 64);
  if ((tid & 63) == 0) red[tid >> 6] = ss;
  __syncthreads();
  const float tot = red[0] + red[1] + red[2] + red[3];
  const float sc = rsqrtf(tot * (1.0f / 1024.0f) + 1e-6f);
  const float4 wv = ((const float4*)wt)[tid];
  ushort4 r;
  r.x = f2bf(v.x * sc * wv.x);
  r.y = f2bf(v.y * sc * wv.y);
  r.z = f2bf(v.z * sc * wv.z);
  r.w = f2bf(v.w * sc * wv.w);
  ((ushort4*)(o + (size_t)row * 1024))[tid] = r;
}

// ---------------------------------------------------------------------------
// 8-wave pipelined GEMM: C[M,N] = A[M,K] @ B[N,K]^T  (bf16 in, fp32 acc)
// CFG 0: 256x256 tile;  CFG 1: 128x128 tile.  BK=32, 4-deep LDS ring.
// Waves 2(M) x 4(N); wave tile (BM/2) x (BN/4); frag layout 16x16x32.
//
// LDS swizzle (T2, both-sides involution): logical (row, colbyte<64) packed
// as beta = (row>>1)*128 + (row&1)*64 + colbyte, then beta ^= ((row>>1)&7)<<4.
// ds_read_b128 of 16 consecutive rows then lands 2 lanes per 16B slot ->
// conflict-free (m136: 2-way is free). gload_lds writes linearly; the global
// SOURCE address is pre-swizzled with the same involution (rule #21).
//
// Pipeline (T3+T4): stage(kt+3) issued at top of iter kt into the ring slot
// whose previous tile (kt-1) was fully consumed last iteration; end-of-iter
// waits are counted (vmcnt(2S) steady / S / 0 tail) + raw s_barrier.
// Epilogues: 2 silu->bf16 | 3 v*aux->bf16 | 4 v+resid->fp32 | 6 qkv/gate split
// ---------------------------------------------------------------------------
template <int CFG, int EPI>
__global__ __launch_bounds__(512, 2) void gemm8w(
    const u16* __restrict__ Ag, const u16* __restrict__ Bg, int N, int K,
    u16* __restrict__ cb, float* __restrict__ cf,
    const u16* __restrict__ aux, const float* __restrict__ resid,
    u16* __restrict__ cb2) {
  constexpr int BM = (CFG == 0) ? 256 : 128;
  constexpr int TB = BM * 64;           // tile bytes (BK=32 cols x 2B)
  constexpr int CPW = TB / 1024 / 8;    // gload chunks per wave per matrix
  constexpr int NI = (BM / 2) / 16;     // A frags per wave (8 / 4)
  constexpr int NJ = (BM / 4) / 16;     // B frags per wave (4 / 2)
  __shared__ __align__(16) char lds[8 * TB];   // A[0..3] then B[0..3]

  const int tid = threadIdx.x;
  const int w = tid >> 6, lane = tid & 63;
  const int wm = w >> 2, wn = w & 3;
  const int g = lane >> 4, r16 = lane & 15;
  const int wr0 = wm * (BM / 2), wc0 = wn * (BM / 4);

  // T1 XCD swizzle (grid.x*grid.y % 8 == 0 for all launches here)
  int bid = blockIdx.y * gridDim.x + blockIdx.x;
  const int cpx = (gridDim.x * gridDim.y) >> 3;
  bid = (bid & 7) * cpx + (bid >> 3);
  const int m0 = (bid / gridDim.x) * BM;
  const int n0 = (bid % gridDim.x) * BM;

  floatx4 acc[NI][NJ];
#pragma unroll
  for (int i = 0; i < NI; i++)
#pragma unroll
    for (int j = 0; j < NJ; j++) acc[i][j] = (floatx4){0.f, 0.f, 0.f, 0.f};

  const int nk = K >> 5;
  const int xorlane = ((lane >> 3) & 7) << 4;

  auto stage = [&](int t) {
    const int bufo = (t & 3) * TB;
    const int k0 = t << 5;
#pragma unroll
    for (int q = 0; q < CPW; ++q) {
      const int c = w + (q << 3);
      const int d = (c << 10) + (lane << 4);
      const int bl = d ^ xorlane;                    // involution
      const int row = ((bl >> 7) << 1) | ((bl >> 6) & 1);
      const int col = (bl & 63) >> 1;
      gload16(Ag + (size_t)(m0 + row) * K + k0 + col,
              (const u16*)(lds + bufo + (c << 10)));
      gload16(Bg + (size_t)(n0 + row) * K + k0 + col,
              (const u16*)(lds + 4 * TB + bufo + (c << 10)));
    }
  };

  // prologue: 3 tiles in flight, consume-ready check is counted
  stage(0); stage(1); stage(2);
  if constexpr (CFG == 0) WAITVM(8); else WAITVM(4);
  blockbar();

  const int xorr = ((r16 >> 1) & 7) << 4;
  const int baseA = ((((wr0 + r16) >> 1) << 7) + ((r16 & 1) << 6) + (g << 4)) ^ xorr;
  const int baseB = ((((wc0 + r16) >> 1) << 7) + ((r16 & 1) << 6) + (g << 4)) ^ xorr;

  for (int kt = 0; kt < nk; ++kt) {
    if (kt + 3 < nk) stage(kt + 3);
    const char* Ab = lds + (kt & 3) * TB;
    const char* Bb = lds + 4 * TB + (kt & 3) * TB;

    short8 af[NI / 2], bfv[NJ];
    // P0: A first half x B first half
#pragma unroll
    for (int q = 0; q < NI / 2; q++) af[q] = *(const short8*)(Ab + baseA + (q << 10));
#pragma unroll
    for (int q = 0; q < NJ / 2; q++) bfv[q] = *(const short8*)(Bb + baseB + (q << 10));
    __builtin_amdgcn_s_setprio(1);
#pragma unroll
    for (int i = 0; i < NI / 2; i++)
#pragma unroll
      for (int j = 0; j < NJ / 2; j++) acc[i][j] = mfma16(af[i], bfv[j], acc[i][j]);
    __builtin_amdgcn_s_setprio(0);
    // P1: A first half x B second half
#pragma unroll
    for (int q = NJ / 2; q < NJ; q++) bfv[q] = *(const short8*)(Bb + baseB + (q << 10));
    __builtin_amdgcn_s_setprio(1);
#pragma unroll
    for (int i = 0; i < NI / 2; i++)
#pragma unroll
      for (int j = NJ / 2; j < NJ; j++) acc[i][j] = mfma16(af[i], bfv[j], acc[i][j]);
    __builtin_amdgcn_s_setprio(0);
    // P2: A second half x B second half
#pragma unroll
    for (int q = 0; q < NI / 2; q++)
      af[q] = *(const short8*)(Ab + baseA + ((NI / 2 + q) << 10));
    __builtin_amdgcn_s_setprio(1);
#pragma unroll
    for (int i = 0; i < NI / 2; i++)
#pragma unroll
      for (int j = NJ / 2; j < NJ; j++)
        acc[NI / 2 + i][j] = mfma16(af[i], bfv[j], acc[NI / 2 + i][j]);
    __builtin_amdgcn_s_setprio(0);
    // P3: A second half x B first half (bfv still live)
    __builtin_amdgcn_s_setprio(1);
#pragma unroll
    for (int i = 0; i < NI / 2; i++)
#pragma unroll
      for (int j = 0; j < NJ / 2; j++)
        acc[NI / 2 + i][j] = mfma16(af[i], bfv[j], acc[NI / 2 + i][j]);
    __builtin_amdgcn_s_setprio(0);

    if (kt + 1 < nk) {            // counted waits: never drain to 0 mid-loop
      if (kt + 3 < nk)      { if constexpr (CFG == 0) WAITVM(8); else WAITVM(4); }
      else if (kt + 2 < nk) { if constexpr (CFG == 0) WAITVM(4); else WAITVM(2); }
      else                  { WAITVM(0); }
      blockbar();
    }
  }

  // epilogue
#pragma unroll
  for (int i = 0; i < NI; i++) {
    const int row = m0 + wr0 + i * 16 + g * 4;
#pragma unroll
    for (int j = 0; j < NJ; j++) {
      const int col = n0 + wc0 + j * 16 + r16;
#pragma unroll
      for (int rr = 0; rr < 4; rr++) {
        const float v = acc[i][j][rr];
        if constexpr (EPI == 2) {
          cb[(size_t)(row + rr) * N + col] = f2bf(v / (1.0f + __expf(-v)));
        } else if constexpr (EPI == 3) {
          const size_t idx = (size_t)(row + rr) * N + col;
          cb[idx] = f2bf(v * bf2f(aux[idx]));
        } else if constexpr (EPI == 4) {
          const size_t idx = (size_t)(row + rr) * N + col;
          cf[idx] = v + resid[idx];
        } else if constexpr (EPI == 6) {
          if (col < 3072)
            cb[(size_t)(row + rr) * 3072 + col] = f2bf(v);
          else
            cb2[(size_t)(row + rr) * 1024 + (col - 3072)] =
                f2bf(1.0f / (1.0f + __expf(-v)));
        }
      }
    }
  }
}

// ---------------------------------------------------------------------------
// Sliding-window causal attention (WINDOW=256) + fused sigmoid-gate multiply.
// (unchanged — validated R1/R2)
// ---------------------------------------------------------------------------
__global__ __launch_bounds__(256) void attn_win_kernel(
    const u16* __restrict__ qkv, const u16* __restrict__ gate,
    u16* __restrict__ out) {
  __shared__ __align__(16) u16 Kl[64][80];
  __shared__ __align__(16) u16 Vt[64][80];
  __shared__ __align__(16) u16 Pl[4][16][80];

  const int tid = threadIdx.x;
  const int w = tid >> 6, lane = tid & 63;
  const int g = lane >> 4, r16 = lane & 15;

  const int q0 = blockIdx.x * 64;
  const int h = blockIdx.y;
  const int b = blockIdx.z;
  const u16* qb_ = qkv + (size_t)b * 2048 * 3072;

  const int tq = q0 + w * 16 + r16;
  const u16* qptr = qb_ + (size_t)tq * 3072 + h * 64;
  const short8 aq0 = *(const short8*)(qptr + g * 8);
  const short8 aq1 = *(const short8*)(qptr + 32 + g * 8);

  floatx4 O[4] = {{0,0,0,0},{0,0,0,0},{0,0,0,0},{0,0,0,0}};
  float mrow[4] = {-1e30f, -1e30f, -1e30f, -1e30f};
  float lrow[4] = {0.f, 0.f, 0.f, 0.f};

  const int srow = tid >> 2;
  const int sq4 = tid & 3;
  const int qw = q0 + w * 16;

  for (int kt = q0 - 256; kt <= q0; kt += 64) {
    if (kt < 0) continue;
    {
      const u16* kb = qb_ + (size_t)(kt + srow) * 3072 + 1024 + h * 64 + sq4 * 16;
      const short8 kv0 = *(const short8*)kb;
      const short8 kv1 = *(const short8*)(kb + 8);
      *(short8*)&Kl[srow][sq4 * 16] = kv0;
      *(short8*)&Kl[srow][sq4 * 16 + 8] = kv1;
      const u16* vb = kb + 1024;
      const short8 vv0 = *(const short8*)vb;
      const short8 vv1 = *(const short8*)(vb + 8);
#pragma unroll
      for (int j = 0; j < 8; j++) Vt[sq4 * 16 + j][srow] = (u16)vv0[j];
#pragma unroll
      for (int j = 0; j < 8; j++) Vt[sq4 * 16 + 8 + j][srow] = (u16)vv1[j];
    }
    __syncthreads();

    const bool active = (qw + 15 >= kt) && (qw - kt < 319);
    if (active) {
      floatx4 S[4];
#pragma unroll
      for (int nf = 0; nf < 4; nf++) {
        const short8 bk0 = *(const short8*)&Kl[nf * 16 + r16][g * 8];
        const short8 bk1 = *(const short8*)&Kl[nf * 16 + r16][32 + g * 8];
        floatx4 a = {0.f, 0.f, 0.f, 0.f};
        a = mfma16(aq0, bk0, a);
        a = mfma16(aq1, bk1, a);
        S[nf] = a;
      }
      float pm[4][4];
      float nmax[4] = {-1e30f, -1e30f, -1e30f, -1e30f};
#pragma unroll
      for (int nf = 0; nf < 4; nf++) {
        const int key = kt + nf * 16 + r16;
#pragma unroll
        for (int rr = 0; rr < 4; rr++) {
          const int q = qw + g * 4 + rr;
          const int dist = q - key;
          const float s = (dist >= 0 && dist < 256) ? S[nf][rr] : -1e30f;
          pm[nf][rr] = s;
          nmax[rr] = fmaxf(nmax[rr], s);
        }
      }
#pragma unroll
      for (int rr = 0; rr < 4; rr++) {
        float v = nmax[rr];
        v = fmaxf(v, __shfl_xor(v, 1, 64));
        v = fmaxf(v, __shfl_xor(v, 2, 64));
        v = fmaxf(v, __shfl_xor(v, 4, 64));
        v = fmaxf(v, __shfl_xor(v, 8, 64));
        const float mnew = fmaxf(mrow[rr], v);
        const float alpha = __expf(0.125f * (mrow[rr] - mnew));
        mrow[rr] = mnew;
        lrow[rr] *= alpha;
#pragma unroll
        for (int n = 0; n < 4; n++) O[n][rr] *= alpha;
        float ls = 0.f;
#pragma unroll
        for (int nf = 0; nf < 4; nf++) {
          const float s = pm[nf][rr];
          const float pv = (s < -1e29f) ? 0.f : __expf(0.125f * (s - mnew));
          pm[nf][rr] = pv;
          ls += pv;
        }
        ls += __shfl_xor(ls, 1, 64);
        ls += __shfl_xor(ls, 2, 64);
        ls += __shfl_xor(ls, 4, 64);
        ls += __shfl_xor(ls, 8, 64);
        lrow[rr] += ls;
      }
#pragma unroll
      for (int nf = 0; nf < 4; nf++)
#pragma unroll
        for (int rr = 0; rr < 4; rr++)
          Pl[w][g * 4 + rr][nf * 16 + r16] = f2bf(pm[nf][rr]);
#pragma unroll
      for (int kf = 0; kf < 2; kf++) {
        const short8 pa = *(const short8*)&Pl[w][r16][kf * 32 + g * 8];
#pragma unroll
        for (int n = 0; n < 4; n++) {
          const short8 vb8 = *(const short8*)&Vt[n * 16 + r16][kf * 32 + g * 8];
          O[n] = mfma16(pa, vb8, O[n]);
        }
      }
    }
    __syncthreads();
  }

#pragma unroll
  for (int n = 0; n < 4; n++) {
#pragma unroll
    for (int rr = 0; rr < 4; rr++) {
      const int t = qw + g * 4 + rr;
      const size_t idx = ((size_t)(b * 2048 + t)) * 1024 + h * 64 + n * 16 + r16;
      const float gv = bf2f(gate[idx]);
      const float ov = (O[n][rr] / lrow[rr]) * gv;
      out[idx] = f2bf(ov);
    }
  }
}

// ---------------------------------------------------------------------------
// Orchestration.
// ---------------------------------------------------------------------------
extern "C" void kernel_launch(void* const* d_in, const int* in_sizes, int n_in,
                              void* d_out, int out_size, void* d_ws,
                              size_t ws_size, hipStream_t stream) {
  (void)in_sizes; (void)n_in; (void)out_size; (void)ws_size;
  const float* x     = (const float*)d_in[0];
  const float* ln1   = (const float*)d_in[1];
  const float* qkvw  = (const float*)d_in[2];
  const float* gatew = (const float*)d_in[3];
  const float* outw  = (const float*)d_in[4];
  const float* ln2   = (const float*)d_in[5];
  const float* wg    = (const float*)d_in[6];
  const float* wu    = (const float*)d_in[7];
  const float* wo    = (const float*)d_in[8];
  float* outp = (float*)d_out;

  u16* p = (u16*)d_ws;
  u16* qkvw_b  = p; p += 3 * 1024 * 1024;   // adjacent to gatew_b (merged B)
  u16* gatew_b = p; p += 1024 * 1024;
  u16* outw_b  = p; p += 1024 * 1024;
  u16* wg_b    = p; p += 4 * 1024 * 1024;
  u16* wu_b    = p; p += 4 * 1024 * 1024;
  u16* wo_b    = p; p += 4 * 1024 * 1024;
  u16* xn      = p; p += 4096 * 1024;
  u16* qkvb    = p; p += (size_t)4096 * 3072;
  u16* gates   = p; p += 4096 * 1024;
  u16* a3      = p; p += 4096 * 1024;
  u16* hb      = p; p += 4096 * 1024;
  u16* gs      = p; p += (size_t)4096 * 4096;
  float* x2    = (float*)p;

  cvt_all_k<<<17408, 256, 0, stream>>>(qkvw, gatew, outw, wg, wu, wo,
                                       qkvw_b, gatew_b, outw_b, wg_b, wu_b, wo_b);

  rmsnorm_k<<<4096, 256, 0, stream>>>(x, ln1, xn);

  // merged qkv+gate: M=4096 N=4096 K=1024, 256^2 tiles, grid 16x16
  gemm8w<0, 6><<<dim3(16, 16), 512, 0, stream>>>(
      xn, qkvw_b, 4096, 1024, qkvb, nullptr, nullptr, nullptr, gates);

  attn_win_kernel<<<dim3(32, 16, 2), 256, 0, stream>>>(qkvb, gates, a3);

  // x2 = x + a3 @ out_w.T : M=4096 N=1024 K=1024, 128^2 tiles, grid 8x32
  gemm8w<1, 4><<<dim3(8, 32), 512, 0, stream>>>(
      a3, outw_b, 1024, 1024, nullptr, x2, nullptr, x, nullptr);

  rmsnorm_k<<<4096, 256, 0, stream>>>(x2, ln2, hb);

  // gs = silu(h @ wg.T); gs *= (h @ wu.T)
  gemm8w<0, 2><<<dim3(16, 16), 512, 0, stream>>>(
      hb, wg_b, 4096, 1024, gs, nullptr, nullptr, nullptr, nullptr);
  gemm8w<0, 3><<<dim3(16, 16), 512, 0, stream>>>(
      hb, wu_b, 4096, 1024, gs, nullptr, gs, nullptr, nullptr);

  // out = x2 + gs @ wo.T : M=4096 N=1024 K=4096, 128^2 tiles, grid 8x32
  gemm8w<1, 4><<<dim3(8, 32), 512, 0, stream>>>(
      gs, wo_b, 1024, 4096, nullptr, outp, nullptr, x2, nullptr);
}

// Round 4
// 364.725 us; speedup vs baseline: 1.2677x; 1.0667x over previous
//
#include <hip/hip_runtime.h>

// ---------------------------------------------------------------------------
// AttentionBlock (RMSNorm -> gated windowed attention -> RMSNorm -> SwiGLU FFN)
// MI355X / gfx950.  R4: m201-style 8-phase GEMM engine. BK=64, kstep-split
// LDS groups (conflict-free frags, linear gload), 2 tile-buffers, per-phase
// {vmcnt -> barrier -> ds_read -> stage -> setprio MFMA}, counted waits only.
// ---------------------------------------------------------------------------

#define DEV __device__ __forceinline__

using u16 = unsigned short;
typedef __attribute__((ext_vector_type(8))) short  short8;   // 8 x bf16
typedef __attribute__((ext_vector_type(4))) float  floatx4;

DEV u16 f2bf(float f) {
  unsigned u = __builtin_bit_cast(unsigned, f);
  u += 0x7FFFu + ((u >> 16) & 1u);
  return (u16)(u >> 16);
}
DEV float bf2f(u16 h) {
  unsigned u = ((unsigned)h) << 16;
  return __builtin_bit_cast(float, u);
}
DEV floatx4 mfma16(short8 a, short8 b, floatx4 c) {
  return __builtin_amdgcn_mfma_f32_16x16x32_bf16(a, b, c, 0, 0, 0);
}
DEV void gload16(const u16* g, const char* lds_base_wave_uniform) {
  __builtin_amdgcn_global_load_lds(
      (const __attribute__((address_space(1))) void*)g,
      (__attribute__((address_space(3))) void*)lds_base_wave_uniform,
      16, 0, 0);
}
#define WAITVM(n) asm volatile("s_waitcnt vmcnt(" #n ")" ::: "memory")
DEV void blockbar() {
  asm volatile("" ::: "memory");
  __builtin_amdgcn_s_barrier();
  asm volatile("" ::: "memory");
}

// ---------------------------------------------------------------------------
// Fused fp32 -> bf16 weight conversion (one launch, 17408 blocks)
// ---------------------------------------------------------------------------
__global__ __launch_bounds__(256) void cvt_all_k(
    const float* __restrict__ s0, const float* __restrict__ s1,
    const float* __restrict__ s2, const float* __restrict__ s3,
    const float* __restrict__ s4, const float* __restrict__ s5,
    u16* __restrict__ d0, u16* __restrict__ d1, u16* __restrict__ d2,
    u16* __restrict__ d3, u16* __restrict__ d4, u16* __restrict__ d5) {
  const int b = blockIdx.x;
  const float* in; u16* out; int base;
  if (b < 3072)       { in = s0; out = d0; base = 0; }
  else if (b < 4096)  { in = s1; out = d1; base = 3072; }
  else if (b < 5120)  { in = s2; out = d2; base = 4096; }
  else if (b < 9216)  { in = s3; out = d3; base = 5120; }
  else if (b < 13312) { in = s4; out = d4; base = 9216; }
  else                { in = s5; out = d5; base = 13312; }
  const size_t i = (size_t)(b - base) * 256 + threadIdx.x;
  const float4 v = ((const float4*)in)[i];
  ushort4 r;
  r.x = f2bf(v.x); r.y = f2bf(v.y); r.z = f2bf(v.z); r.w = f2bf(v.w);
  ((ushort4*)out)[i] = r;
}

// ---------------------------------------------------------------------------
// RMSNorm: one block per row (1024 cols), fp32 in -> bf16 out
// ---------------------------------------------------------------------------
__global__ __launch_bounds__(256) void rmsnorm_k(const float* __restrict__ x,
                                                 const float* __restrict__ wt,
                                                 u16* __restrict__ o) {
  __shared__ float red[4];
  const int row = blockIdx.x;
  const int tid = threadIdx.x;
  const float4 v = ((const float4*)(x + (size_t)row * 1024))[tid];
  float ss = v.x * v.x + v.y * v.y + v.z * v.z + v.w * v.w;
  ss += __shfl_xor(ss, 1, 64);
  ss += __shfl_xor(ss, 2, 64);
  ss += __shfl_xor(ss, 4, 64);
  ss += __shfl_xor(ss, 8, 64);
  ss += __shfl_xor(ss, 16, 64);
  ss += __shfl_xor(ss, 32, 64);
  if ((tid & 63) == 0) red[tid >> 6] = ss;
  __syncthreads();
  const float tot = red[0] + red[1] + red[2] + red[3];
  const float sc = rsqrtf(tot * (1.0f / 1024.0f) + 1e-6f);
  const float4 wv = ((const float4*)wt)[tid];
  ushort4 r;
  r.x = f2bf(v.x * sc * wv.x);
  r.y = f2bf(v.y * sc * wv.y);
  r.z = f2bf(v.z * sc * wv.z);
  r.w = f2bf(v.w * sc * wv.w);
  ((ushort4*)(o + (size_t)row * 1024))[tid] = r;
}

// ---------------------------------------------------------------------------
// 8-phase pipelined GEMM: C[M,N] = A[M,K] @ B[N,K]^T  (bf16 in, fp32 acc)
// CFG0: 256x256, 8 waves (2x4), 512 thr, LDS 128 KiB (1 block/CU).
// CFG1: 128x128, 4 waves (2x2), 256 thr, LDS  64 KiB (2 blocks/CU).
// BK=64. LDS tile buffer = groups [A_ks0 | A_ks1 | B_ks0 | B_ks1], each
// [BM][32] bf16 row-major (64 B rows). Frag ds_read_b128 of 16 consecutive
// rows = contiguous 1 KB -> conflict-free; gload_lds dest is linear.
// 2 buffers: tile t reads buf(t&1), all stages during t write buf^1.
//
// Stage group ledger (CFG0), issue order per tile t -> for t+1:
//   P0:A_ks1  P1:B_ks0  P2:A_ks0  P3:B_ks1   (prologue: same order for t=0)
// in-flight at P0(t): [A1(t),B0(t),A0(t),B1(t)] need A0 -> vmcnt(2)
// in-flight at P2(t): [B1(t),A1(t+1),B0(t+1)] need B1 -> vmcnt(4); tail 0.
// CFG1 (2 phases): E0:{A0,B0}(t+1), E1:{A1,B1}(t+1); vmcnt(4)/vmcnt(4)/tail 0.
// Epilogues: 2 silu | 3 v*aux | 4 v+resid fp32 | 6 qkv/gate split
// ---------------------------------------------------------------------------
template <int CFG, int EPI>
__global__ __launch_bounds__((CFG == 0) ? 512 : 256, 2) void gemm8p(
    const u16* __restrict__ Ag, const u16* __restrict__ Bg, int N, int K,
    u16* __restrict__ cb, float* __restrict__ cf,
    const u16* __restrict__ aux, const float* __restrict__ resid,
    u16* __restrict__ cb2) {
  constexpr int BM = (CFG == 0) ? 256 : 128;
  constexpr int NWAVES = (CFG == 0) ? 8 : 4;
  constexpr int WAVES_N = (CFG == 0) ? 4 : 2;
  constexpr int WM = (CFG == 0) ? 128 : 64;   // BM / 2
  constexpr int NI = WM / 16;                  // 8 / 4
  constexpr int NJ = 4;                        // 64 / 16
  constexpr int IH = (CFG == 0) ? NI / 2 : NI; // frags per phase (4 / 4)
  constexpr int GB = BM * 64;                  // group bytes
  constexpr int BUFB = 4 * GB;
  __shared__ __align__(16) char lds[2 * BUFB];

  const int tid = threadIdx.x;
  const int w = tid >> 6, lane = tid & 63;
  const int wm = w / WAVES_N, wn = w % WAVES_N;
  const int g = lane >> 4, r16 = lane & 15;

  // T1 XCD swizzle (grid.x*grid.y == 256 for all launches here)
  int bid = blockIdx.y * gridDim.x + blockIdx.x;
  const int cpx = (gridDim.x * gridDim.y) >> 3;
  bid = (bid & 7) * cpx + (bid >> 3);
  const int m0 = (bid / gridDim.x) * BM;
  const int n0 = (bid % gridDim.x) * BM;

  floatx4 acc[NI][NJ];
#pragma unroll
  for (int i = 0; i < NI; i++)
#pragma unroll
    for (int j = 0; j < NJ; j++) acc[i][j] = (floatx4){0.f, 0.f, 0.f, 0.f};

  const int nt = K >> 6;

  // stage one 16 KB group G (0:A_ks0 1:A_ks1 2:B_ks0 3:B_ks1) of tile t
  const int srow = w * 32 + (lane >> 2);       // per-wave 32 rows, 2 gloads
  const int scol8 = (lane & 3) * 8;
  auto stageG = [&](int G, int t) {
    if (t >= nt) return;
    const u16* Mat = (G < 2) ? Ag : Bg;
    const int base0 = (G < 2) ? m0 : n0;
    const int kc = t * 64 + (G & 1) * 32 + scol8;
    const char* dst = lds + (t & 1) * BUFB + G * GB + w * 2048;
#pragma unroll
    for (int q = 0; q < 2; q++)
      gload16(Mat + (size_t)(base0 + srow + q * 16) * K + kc, dst + q * 1024);
  };

  auto rdA = [&](short8* af, int ks, int ihalf, const char* buf) {
#pragma unroll
    for (int i = 0; i < IH; i++) {
      const int arow = wm * WM + (ihalf * IH + i) * 16 + r16;
      af[i] = *(const short8*)(buf + ks * GB + arow * 64 + g * 16);
    }
  };
  auto rdB = [&](short8* bf_, int ks, const char* buf) {
#pragma unroll
    for (int j = 0; j < NJ; j++) {
      const int brow = wn * 64 + j * 16 + r16;
      bf_[j] = *(const short8*)(buf + 2 * GB + ks * GB + brow * 64 + g * 16);
    }
  };
  auto mm = [&](short8* af, short8* bf_, int ihalf) {
    __builtin_amdgcn_s_setprio(1);
#pragma unroll
    for (int i = 0; i < IH; i++)
#pragma unroll
      for (int j = 0; j < NJ; j++)
        acc[ihalf * IH + i][j] = mfma16(af[i], bf_[j], acc[ihalf * IH + i][j]);
    __builtin_amdgcn_s_setprio(0);
  };

  // prologue: stage tile 0 in the ledger's issue order
  if constexpr (CFG == 0) { stageG(1, 0); stageG(2, 0); stageG(0, 0); stageG(3, 0); }
  else                    { stageG(0, 0); stageG(2, 0); stageG(1, 0); stageG(3, 0); }

  for (int t = 0; t < nt; ++t) {
    const char* buf = lds + (t & 1) * BUFB;
    short8 af[IH], bfv[NJ];
    if constexpr (CFG == 0) {
      // P0: (ks0, ih0)
      WAITVM(2);
      blockbar();
      rdA(af, 0, 0, buf); rdB(bfv, 0, buf);
      stageG(1, t + 1);
      mm(af, bfv, 0);
      // P1: (ks0, ih1)
      blockbar();
      rdA(af, 0, 1, buf);
      stageG(2, t + 1);
      mm(af, bfv, 1);
      // P2: (ks1, ih0)
      if (t + 1 < nt) { WAITVM(4); } else { WAITVM(0); }
      blockbar();
      rdA(af, 1, 0, buf); rdB(bfv, 1, buf);
      stageG(0, t + 1);
      mm(af, bfv, 0);
      // P3: (ks1, ih1)
      blockbar();
      rdA(af, 1, 1, buf);
      stageG(3, t + 1);
      mm(af, bfv, 1);
    } else {
      // E0: ks0, all i
      WAITVM(4);
      blockbar();
      rdA(af, 0, 0, buf); rdB(bfv, 0, buf);
      stageG(0, t + 1); stageG(2, t + 1);
      mm(af, bfv, 0);
      // E1: ks1, all i
      if (t + 1 < nt) { WAITVM(4); } else { WAITVM(0); }
      blockbar();
      rdA(af, 1, 0, buf); rdB(bfv, 1, buf);
      stageG(1, t + 1); stageG(3, t + 1);
      mm(af, bfv, 0);
    }
  }

  // epilogue
#pragma unroll
  for (int i = 0; i < NI; i++) {
    const int row = m0 + wm * WM + i * 16 + g * 4;
#pragma unroll
    for (int j = 0; j < NJ; j++) {
      const int col = n0 + wn * 64 + j * 16 + r16;
#pragma unroll
      for (int rr = 0; rr < 4; rr++) {
        const float v = acc[i][j][rr];
        if constexpr (EPI == 2) {
          cb[(size_t)(row + rr) * N + col] = f2bf(v / (1.0f + __expf(-v)));
        } else if constexpr (EPI == 3) {
          const size_t idx = (size_t)(row + rr) * N + col;
          cb[idx] = f2bf(v * bf2f(aux[idx]));
        } else if constexpr (EPI == 4) {
          const size_t idx = (size_t)(row + rr) * N + col;
          cf[idx] = v + resid[idx];
        } else if constexpr (EPI == 6) {
          if (col < 3072)
            cb[(size_t)(row + rr) * 3072 + col] = f2bf(v);
          else
            cb2[(size_t)(row + rr) * 1024 + (col - 3072)] =
                f2bf(1.0f / (1.0f + __expf(-v)));
        }
      }
    }
  }
}

// ---------------------------------------------------------------------------
// Sliding-window causal attention (WINDOW=256) + fused sigmoid-gate multiply.
// (unchanged — validated R1-R3)
// ---------------------------------------------------------------------------
__global__ __launch_bounds__(256) void attn_win_kernel(
    const u16* __restrict__ qkv, const u16* __restrict__ gate,
    u16* __restrict__ out) {
  __shared__ __align__(16) u16 Kl[64][80];
  __shared__ __align__(16) u16 Vt[64][80];
  __shared__ __align__(16) u16 Pl[4][16][80];

  const int tid = threadIdx.x;
  const int w = tid >> 6, lane = tid & 63;
  const int g = lane >> 4, r16 = lane & 15;

  const int q0 = blockIdx.x * 64;
  const int h = blockIdx.y;
  const int b = blockIdx.z;
  const u16* qb_ = qkv + (size_t)b * 2048 * 3072;

  const int tq = q0 + w * 16 + r16;
  const u16* qptr = qb_ + (size_t)tq * 3072 + h * 64;
  const short8 aq0 = *(const short8*)(qptr + g * 8);
  const short8 aq1 = *(const short8*)(qptr + 32 + g * 8);

  floatx4 O[4] = {{0,0,0,0},{0,0,0,0},{0,0,0,0},{0,0,0,0}};
  float mrow[4] = {-1e30f, -1e30f, -1e30f, -1e30f};
  float lrow[4] = {0.f, 0.f, 0.f, 0.f};

  const int srow = tid >> 2;
  const int sq4 = tid & 3;
  const int qw = q0 + w * 16;

  for (int kt = q0 - 256; kt <= q0; kt += 64) {
    if (kt < 0) continue;
    {
      const u16* kb = qb_ + (size_t)(kt + srow) * 3072 + 1024 + h * 64 + sq4 * 16;
      const short8 kv0 = *(const short8*)kb;
      const short8 kv1 = *(const short8*)(kb + 8);
      *(short8*)&Kl[srow][sq4 * 16] = kv0;
      *(short8*)&Kl[srow][sq4 * 16 + 8] = kv1;
      const u16* vb = kb + 1024;
      const short8 vv0 = *(const short8*)vb;
      const short8 vv1 = *(const short8*)(vb + 8);
#pragma unroll
      for (int j = 0; j < 8; j++) Vt[sq4 * 16 + j][srow] = (u16)vv0[j];
#pragma unroll
      for (int j = 0; j < 8; j++) Vt[sq4 * 16 + 8 + j][srow] = (u16)vv1[j];
    }
    __syncthreads();

    const bool active = (qw + 15 >= kt) && (qw - kt < 319);
    if (active) {
      floatx4 S[4];
#pragma unroll
      for (int nf = 0; nf < 4; nf++) {
        const short8 bk0 = *(const short8*)&Kl[nf * 16 + r16][g * 8];
        const short8 bk1 = *(const short8*)&Kl[nf * 16 + r16][32 + g * 8];
        floatx4 a = {0.f, 0.f, 0.f, 0.f};
        a = mfma16(aq0, bk0, a);
        a = mfma16(aq1, bk1, a);
        S[nf] = a;
      }
      float pm[4][4];
      float nmax[4] = {-1e30f, -1e30f, -1e30f, -1e30f};
#pragma unroll
      for (int nf = 0; nf < 4; nf++) {
        const int key = kt + nf * 16 + r16;
#pragma unroll
        for (int rr = 0; rr < 4; rr++) {
          const int q = qw + g * 4 + rr;
          const int dist = q - key;
          const float s = (dist >= 0 && dist < 256) ? S[nf][rr] : -1e30f;
          pm[nf][rr] = s;
          nmax[rr] = fmaxf(nmax[rr], s);
        }
      }
#pragma unroll
      for (int rr = 0; rr < 4; rr++) {
        float v = nmax[rr];
        v = fmaxf(v, __shfl_xor(v, 1, 64));
        v = fmaxf(v, __shfl_xor(v, 2, 64));
        v = fmaxf(v, __shfl_xor(v, 4, 64));
        v = fmaxf(v, __shfl_xor(v, 8, 64));
        const float mnew = fmaxf(mrow[rr], v);
        const float alpha = __expf(0.125f * (mrow[rr] - mnew));
        mrow[rr] = mnew;
        lrow[rr] *= alpha;
#pragma unroll
        for (int n = 0; n < 4; n++) O[n][rr] *= alpha;
        float ls = 0.f;
#pragma unroll
        for (int nf = 0; nf < 4; nf++) {
          const float s = pm[nf][rr];
          const float pv = (s < -1e29f) ? 0.f : __expf(0.125f * (s - mnew));
          pm[nf][rr] = pv;
          ls += pv;
        }
        ls += __shfl_xor(ls, 1, 64);
        ls += __shfl_xor(ls, 2, 64);
        ls += __shfl_xor(ls, 4, 64);
        ls += __shfl_xor(ls, 8, 64);
        lrow[rr] += ls;
      }
#pragma unroll
      for (int nf = 0; nf < 4; nf++)
#pragma unroll
        for (int rr = 0; rr < 4; rr++)
          Pl[w][g * 4 + rr][nf * 16 + r16] = f2bf(pm[nf][rr]);
#pragma unroll
      for (int kf = 0; kf < 2; kf++) {
        const short8 pa = *(const short8*)&Pl[w][r16][kf * 32 + g * 8];
#pragma unroll
        for (int n = 0; n < 4; n++) {
          const short8 vb8 = *(const short8*)&Vt[n * 16 + r16][kf * 32 + g * 8];
          O[n] = mfma16(pa, vb8, O[n]);
        }
      }
    }
    __syncthreads();
  }

#pragma unroll
  for (int n = 0; n < 4; n++) {
#pragma unroll
    for (int rr = 0; rr < 4; rr++) {
      const int t = qw + g * 4 + rr;
      const size_t idx = ((size_t)(b * 2048 + t)) * 1024 + h * 64 + n * 16 + r16;
      const float gv = bf2f(gate[idx]);
      const float ov = (O[n][rr] / lrow[rr]) * gv;
      out[idx] = f2bf(ov);
    }
  }
}

// ---------------------------------------------------------------------------
// Orchestration.
// ---------------------------------------------------------------------------
extern "C" void kernel_launch(void* const* d_in, const int* in_sizes, int n_in,
                              void* d_out, int out_size, void* d_ws,
                              size_t ws_size, hipStream_t stream) {
  (void)in_sizes; (void)n_in; (void)out_size; (void)ws_size;
  const float* x     = (const float*)d_in[0];
  const float* ln1   = (const float*)d_in[1];
  const float* qkvw  = (const float*)d_in[2];
  const float* gatew = (const float*)d_in[3];
  const float* outw  = (const float*)d_in[4];
  const float* ln2   = (const float*)d_in[5];
  const float* wg    = (const float*)d_in[6];
  const float* wu    = (const float*)d_in[7];
  const float* wo    = (const float*)d_in[8];
  float* outp = (float*)d_out;

  u16* p = (u16*)d_ws;
  u16* qkvw_b  = p; p += 3 * 1024 * 1024;   // adjacent to gatew_b (merged B)
  u16* gatew_b = p; p += 1024 * 1024;
  u16* outw_b  = p; p += 1024 * 1024;
  u16* wg_b    = p; p += 4 * 1024 * 1024;
  u16* wu_b    = p; p += 4 * 1024 * 1024;
  u16* wo_b    = p; p += 4 * 1024 * 1024;
  u16* xn      = p; p += 4096 * 1024;
  u16* qkvb    = p; p += (size_t)4096 * 3072;
  u16* gates   = p; p += 4096 * 1024;
  u16* a3      = p; p += 4096 * 1024;
  u16* hb      = p; p += 4096 * 1024;
  u16* gs      = p; p += (size_t)4096 * 4096;
  float* x2    = (float*)p;

  cvt_all_k<<<17408, 256, 0, stream>>>(qkvw, gatew, outw, wg, wu, wo,
                                       qkvw_b, gatew_b, outw_b, wg_b, wu_b, wo_b);

  rmsnorm_k<<<4096, 256, 0, stream>>>(x, ln1, xn);

  // merged qkv+gate: M=4096 N=4096 K=1024, 256^2 tiles, grid 16x16
  gemm8p<0, 6><<<dim3(16, 16), 512, 0, stream>>>(
      xn, qkvw_b, 4096, 1024, qkvb, nullptr, nullptr, nullptr, gates);

  attn_win_kernel<<<dim3(32, 16, 2), 256, 0, stream>>>(qkvb, gates, a3);

  // x2 = x + a3 @ out_w.T : M=4096 N=1024 K=1024, 128^2 tiles, grid 8x32
  gemm8p<1, 4><<<dim3(8, 32), 256, 0, stream>>>(
      a3, outw_b, 1024, 1024, nullptr, x2, nullptr, x, nullptr);

  rmsnorm_k<<<4096, 256, 0, stream>>>(x2, ln2, hb);

  // gs = silu(h @ wg.T); gs *= (h @ wu.T)
  gemm8p<0, 2><<<dim3(16, 16), 512, 0, stream>>>(
      hb, wg_b, 4096, 1024, gs, nullptr, nullptr, nullptr, nullptr);
  gemm8p<0, 3><<<dim3(16, 16), 512, 0, stream>>>(
      hb, wu_b, 4096, 1024, gs, nullptr, gs, nullptr, nullptr);

  // out = x2 + gs @ wo.T : M=4096 N=1024 K=4096, 128^2 tiles, grid 8x32
  gemm8p<1, 4><<<dim3(8, 32), 256, 0, stream>>>(
      gs, wo_b, 1024, 4096, nullptr, outp, nullptr, x2, nullptr);
}

// Round 5
// 359.998 us; speedup vs baseline: 1.2844x; 1.0131x over previous
//
#include <hip/hip_runtime.h>

// ---------------------------------------------------------------------------
// AttentionBlock (RMSNorm -> gated windowed attention -> RMSNorm -> SwiGLU FFN)
// MI355X / gfx950.  R5: 8-phase GEMM engine + slot-XOR LDS swizzle
// (slot' = g ^ ((row>>1)&3), both-sides involution; R3 measured 0 conflicts
// with the equivalent spread), CFG1 widened to 8 waves / 512 thr.
// ---------------------------------------------------------------------------

#define DEV __device__ __forceinline__

using u16 = unsigned short;
typedef __attribute__((ext_vector_type(8))) short  short8;   // 8 x bf16
typedef __attribute__((ext_vector_type(4))) float  floatx4;

DEV u16 f2bf(float f) {
  unsigned u = __builtin_bit_cast(unsigned, f);
  u += 0x7FFFu + ((u >> 16) & 1u);
  return (u16)(u >> 16);
}
DEV float bf2f(u16 h) {
  unsigned u = ((unsigned)h) << 16;
  return __builtin_bit_cast(float, u);
}
DEV floatx4 mfma16(short8 a, short8 b, floatx4 c) {
  return __builtin_amdgcn_mfma_f32_16x16x32_bf16(a, b, c, 0, 0, 0);
}
DEV void gload16(const u16* g, const char* lds_base_wave_uniform) {
  __builtin_amdgcn_global_load_lds(
      (const __attribute__((address_space(1))) void*)g,
      (__attribute__((address_space(3))) void*)lds_base_wave_uniform,
      16, 0, 0);
}
#define WAITVM(n) asm volatile("s_waitcnt vmcnt(" #n ")" ::: "memory")
DEV void blockbar() {
  asm volatile("" ::: "memory");
  __builtin_amdgcn_s_barrier();
  asm volatile("" ::: "memory");
}

// ---------------------------------------------------------------------------
// Fused fp32 -> bf16 weight conversion (one launch, 17408 blocks)
// ---------------------------------------------------------------------------
__global__ __launch_bounds__(256) void cvt_all_k(
    const float* __restrict__ s0, const float* __restrict__ s1,
    const float* __restrict__ s2, const float* __restrict__ s3,
    const float* __restrict__ s4, const float* __restrict__ s5,
    u16* __restrict__ d0, u16* __restrict__ d1, u16* __restrict__ d2,
    u16* __restrict__ d3, u16* __restrict__ d4, u16* __restrict__ d5) {
  const int b = blockIdx.x;
  const float* in; u16* out; int base;
  if (b < 3072)       { in = s0; out = d0; base = 0; }
  else if (b < 4096)  { in = s1; out = d1; base = 3072; }
  else if (b < 5120)  { in = s2; out = d2; base = 4096; }
  else if (b < 9216)  { in = s3; out = d3; base = 5120; }
  else if (b < 13312) { in = s4; out = d4; base = 9216; }
  else                { in = s5; out = d5; base = 13312; }
  const size_t i = (size_t)(b - base) * 256 + threadIdx.x;
  const float4 v = ((const float4*)in)[i];
  ushort4 r;
  r.x = f2bf(v.x); r.y = f2bf(v.y); r.z = f2bf(v.z); r.w = f2bf(v.w);
  ((ushort4*)out)[i] = r;
}

// ---------------------------------------------------------------------------
// RMSNorm: one block per row (1024 cols), fp32 in -> bf16 out
// ---------------------------------------------------------------------------
__global__ __launch_bounds__(256) void rmsnorm_k(const float* __restrict__ x,
                                                 const float* __restrict__ wt,
                                                 u16* __restrict__ o) {
  __shared__ float red[4];
  const int row = blockIdx.x;
  const int tid = threadIdx.x;
  const float4 v = ((const float4*)(x + (size_t)row * 1024))[tid];
  float ss = v.x * v.x + v.y * v.y + v.z * v.z + v.w * v.w;
  ss += __shfl_xor(ss, 1, 64);
  ss += __shfl_xor(ss, 2, 64);
  ss += __shfl_xor(ss, 4, 64);
  ss += __shfl_xor(ss, 8, 64);
  ss += __shfl_xor(ss, 16, 64);
  ss += __shfl_xor(ss, 32, 64);
  if ((tid & 63) == 0) red[tid >> 6] = ss;
  __syncthreads();
  const float tot = red[0] + red[1] + red[2] + red[3];
  const float sc = rsqrtf(tot * (1.0f / 1024.0f) + 1e-6f);
  const float4 wv = ((const float4*)wt)[tid];
  ushort4 r;
  r.x = f2bf(v.x * sc * wv.x);
  r.y = f2bf(v.y * sc * wv.y);
  r.z = f2bf(v.z * sc * wv.z);
  r.w = f2bf(v.w * sc * wv.w);
  ((ushort4*)(o + (size_t)row * 1024))[tid] = r;
}

// ---------------------------------------------------------------------------
// 8-phase pipelined GEMM: C[M,N] = A[M,K] @ B[N,K]^T  (bf16 in, fp32 acc)
// Both CFGs: 512 thr, 8 waves as 2(M) x 4(N).
// CFG0: 256x256 tile, wave tile 128x64, 4 phases/tile, LDS 128 KiB.
// CFG1: 128x128 tile, wave tile  64x32, 2 phases/tile, LDS  64 KiB.
// BK=64. Groups [A_ks0 | A_ks1 | B_ks0 | B_ks1], each [BM][64B].
//
// LDS swizzle: logical (row, kgroup g in 0..3) stored at byte
//   row*64 + ((g ^ ((row>>1)&3)) << 4)
// -> every 16-lane read group covers all 8 16B bank-slots x2 (conflict-free;
// R3-validated spread). gload_lds dest is LINEAR; the involution is applied
// to the global SOURCE k-group instead: kg_src = (lane&3) ^ ((lane>>3)&3).
//
// Stage ledger (issue order per tile t for t+1): A0, B0, A1, B1.
//   need (A0,B0) at phase ks0 -> allow {A1,B1}  => vmcnt(2 groups)
//   need (A1,B1) at phase ks1 -> allow {A0,B0}(t+1) => vmcnt(2 groups)
// groups are QI loads/lane (CFG0: 2 -> vmcnt(4); CFG1: 1 -> vmcnt(2)).
// Epilogues: 2 silu | 3 v*aux | 4 v+resid fp32 | 6 qkv/gate split
// ---------------------------------------------------------------------------
template <int CFG, int EPI>
__global__ __launch_bounds__(512, 2) void gemm8p(
    const u16* __restrict__ Ag, const u16* __restrict__ Bg, int N, int K,
    u16* __restrict__ cb, float* __restrict__ cf,
    const u16* __restrict__ aux, const float* __restrict__ resid,
    u16* __restrict__ cb2) {
  constexpr int BM = (CFG == 0) ? 256 : 128;
  constexpr int WM = (CFG == 0) ? 128 : 64;
  constexpr int WN = (CFG == 0) ? 64 : 32;
  constexpr int NI = WM / 16;                  // 8 / 4
  constexpr int NJ = WN / 16;                  // 4 / 2
  constexpr int IH = (CFG == 0) ? NI / 2 : NI; // frags per mm (4 / 4)
  constexpr int GB = BM * 64;                  // group bytes: 16K / 8K
  constexpr int QI = (CFG == 0) ? 2 : 1;       // gloads per lane per group
  constexpr int BUFB = 4 * GB;
  __shared__ __align__(16) char lds[2 * BUFB];

  const int tid = threadIdx.x;
  const int w = tid >> 6, lane = tid & 63;
  const int wm = w >> 2, wn = w & 3;
  const int g = lane >> 4, r16 = lane & 15;
  const int gx = (g ^ ((r16 >> 1) & 3)) << 4;  // swizzled 16B slot offset

  // T1 XCD swizzle (grid.x*grid.y == 256 for all launches here)
  int bid = blockIdx.y * gridDim.x + blockIdx.x;
  const int cpx = (gridDim.x * gridDim.y) >> 3;
  bid = (bid & 7) * cpx + (bid >> 3);
  const int m0 = (bid / gridDim.x) * BM;
  const int n0 = (bid % gridDim.x) * BM;

  floatx4 acc[NI][NJ];
#pragma unroll
  for (int i = 0; i < NI; i++)
#pragma unroll
    for (int j = 0; j < NJ; j++) acc[i][j] = (floatx4){0.f, 0.f, 0.f, 0.f};

  const int nt = K >> 6;

  // stage one group G (0:A_ks0 1:A_ks1 2:B_ks0 3:B_ks1) of tile t
  const int kg_src = (lane & 3) ^ ((lane >> 3) & 3);  // inverse swizzle
  auto stageG = [&](int G, int t) {
    if (t >= nt) return;
    const u16* Mat = (G < 2) ? Ag : Bg;
    const int b0 = (G < 2) ? m0 : n0;
    const int kc = t * 64 + (G & 1) * 32 + kg_src * 8;
    const char* dst = lds + (t & 1) * BUFB + G * GB + w * 1024;
#pragma unroll
    for (int q = 0; q < QI; q++) {
      const int row = q * 128 + w * 16 + (lane >> 2);
      gload16(Mat + (size_t)(b0 + row) * K + kc, dst + q * 8192);
    }
  };

  auto rdA = [&](short8* af, int ks, int ihalf, const char* buf) {
#pragma unroll
    for (int i = 0; i < IH; i++) {
      const int arow = wm * WM + (ihalf * IH + i) * 16 + r16;
      af[i] = *(const short8*)(buf + ks * GB + arow * 64 + gx);
    }
  };
  auto rdB = [&](short8* bf_, int ks, const char* buf) {
#pragma unroll
    for (int j = 0; j < NJ; j++) {
      const int brow = wn * WN + j * 16 + r16;
      bf_[j] = *(const short8*)(buf + 2 * GB + ks * GB + brow * 64 + gx);
    }
  };
  auto mm = [&](short8* af, short8* bf_, int ihalf) {
    __builtin_amdgcn_s_setprio(1);
#pragma unroll
    for (int i = 0; i < IH; i++)
#pragma unroll
      for (int j = 0; j < NJ; j++)
        acc[ihalf * IH + i][j] = mfma16(af[i], bf_[j], acc[ihalf * IH + i][j]);
    __builtin_amdgcn_s_setprio(0);
  };

  // prologue: tile 0 in ledger order A0, B0, A1, B1
  stageG(0, 0); stageG(2, 0); stageG(1, 0); stageG(3, 0);

  for (int t = 0; t < nt; ++t) {
    const char* buf = lds + (t & 1) * BUFB;
    short8 af[IH], bfv[NJ];
    if constexpr (CFG == 0) {
      // P0: ks0, ih0
      WAITVM(4);
      blockbar();
      rdA(af, 0, 0, buf); rdB(bfv, 0, buf);
      stageG(0, t + 1);
      mm(af, bfv, 0);
      // P1: ks0, ih1
      blockbar();
      rdA(af, 0, 1, buf);
      stageG(2, t + 1);
      mm(af, bfv, 1);
      // P2: ks1, ih0
      if (t + 1 < nt) { WAITVM(4); } else { WAITVM(0); }
      blockbar();
      rdA(af, 1, 0, buf); rdB(bfv, 1, buf);
      stageG(1, t + 1);
      mm(af, bfv, 0);
      // P3: ks1, ih1
      blockbar();
      rdA(af, 1, 1, buf);
      stageG(3, t + 1);
      mm(af, bfv, 1);
    } else {
      // E0: ks0, all i
      WAITVM(2);
      blockbar();
      rdA(af, 0, 0, buf); rdB(bfv, 0, buf);
      stageG(0, t + 1); stageG(2, t + 1);
      mm(af, bfv, 0);
      // E1: ks1, all i
      if (t + 1 < nt) { WAITVM(2); } else { WAITVM(0); }
      blockbar();
      rdA(af, 1, 0, buf); rdB(bfv, 1, buf);
      stageG(1, t + 1); stageG(3, t + 1);
      mm(af, bfv, 0);
    }
  }

  // epilogue
#pragma unroll
  for (int i = 0; i < NI; i++) {
    const int row = m0 + wm * WM + i * 16 + g * 4;
#pragma unroll
    for (int j = 0; j < NJ; j++) {
      const int col = n0 + wn * WN + j * 16 + r16;
#pragma unroll
      for (int rr = 0; rr < 4; rr++) {
        const float v = acc[i][j][rr];
        if constexpr (EPI == 2) {
          cb[(size_t)(row + rr) * N + col] = f2bf(v / (1.0f + __expf(-v)));
        } else if constexpr (EPI == 3) {
          const size_t idx = (size_t)(row + rr) * N + col;
          cb[idx] = f2bf(v * bf2f(aux[idx]));
        } else if constexpr (EPI == 4) {
          const size_t idx = (size_t)(row + rr) * N + col;
          cf[idx] = v + resid[idx];
        } else if constexpr (EPI == 6) {
          if (col < 3072)
            cb[(size_t)(row + rr) * 3072 + col] = f2bf(v);
          else
            cb2[(size_t)(row + rr) * 1024 + (col - 3072)] =
                f2bf(1.0f / (1.0f + __expf(-v)));
        }
      }
    }
  }
}

// ---------------------------------------------------------------------------
// Sliding-window causal attention (WINDOW=256) + fused sigmoid-gate multiply.
// (unchanged — validated R1-R4)
// ---------------------------------------------------------------------------
__global__ __launch_bounds__(256) void attn_win_kernel(
    const u16* __restrict__ qkv, const u16* __restrict__ gate,
    u16* __restrict__ out) {
  __shared__ __align__(16) u16 Kl[64][80];
  __shared__ __align__(16) u16 Vt[64][80];
  __shared__ __align__(16) u16 Pl[4][16][80];

  const int tid = threadIdx.x;
  const int w = tid >> 6, lane = tid & 63;
  const int g = lane >> 4, r16 = lane & 15;

  const int q0 = blockIdx.x * 64;
  const int h = blockIdx.y;
  const int b = blockIdx.z;
  const u16* qb_ = qkv + (size_t)b * 2048 * 3072;

  const int tq = q0 + w * 16 + r16;
  const u16* qptr = qb_ + (size_t)tq * 3072 + h * 64;
  const short8 aq0 = *(const short8*)(qptr + g * 8);
  const short8 aq1 = *(const short8*)(qptr + 32 + g * 8);

  floatx4 O[4] = {{0,0,0,0},{0,0,0,0},{0,0,0,0},{0,0,0,0}};
  float mrow[4] = {-1e30f, -1e30f, -1e30f, -1e30f};
  float lrow[4] = {0.f, 0.f, 0.f, 0.f};

  const int srow = tid >> 2;
  const int sq4 = tid & 3;
  const int qw = q0 + w * 16;

  for (int kt = q0 - 256; kt <= q0; kt += 64) {
    if (kt < 0) continue;
    {
      const u16* kb = qb_ + (size_t)(kt + srow) * 3072 + 1024 + h * 64 + sq4 * 16;
      const short8 kv0 = *(const short8*)kb;
      const short8 kv1 = *(const short8*)(kb + 8);
      *(short8*)&Kl[srow][sq4 * 16] = kv0;
      *(short8*)&Kl[srow][sq4 * 16 + 8] = kv1;
      const u16* vb = kb + 1024;
      const short8 vv0 = *(const short8*)vb;
      const short8 vv1 = *(const short8*)(vb + 8);
#pragma unroll
      for (int j = 0; j < 8; j++) Vt[sq4 * 16 + j][srow] = (u16)vv0[j];
#pragma unroll
      for (int j = 0; j < 8; j++) Vt[sq4 * 16 + 8 + j][srow] = (u16)vv1[j];
    }
    __syncthreads();

    const bool active = (qw + 15 >= kt) && (qw - kt < 319);
    if (active) {
      floatx4 S[4];
#pragma unroll
      for (int nf = 0; nf < 4; nf++) {
        const short8 bk0 = *(const short8*)&Kl[nf * 16 + r16][g * 8];
        const short8 bk1 = *(const short8*)&Kl[nf * 16 + r16][32 + g * 8];
        floatx4 a = {0.f, 0.f, 0.f, 0.f};
        a = mfma16(aq0, bk0, a);
        a = mfma16(aq1, bk1, a);
        S[nf] = a;
      }
      float pm[4][4];
      float nmax[4] = {-1e30f, -1e30f, -1e30f, -1e30f};
#pragma unroll
      for (int nf = 0; nf < 4; nf++) {
        const int key = kt + nf * 16 + r16;
#pragma unroll
        for (int rr = 0; rr < 4; rr++) {
          const int q = qw + g * 4 + rr;
          const int dist = q - key;
          const float s = (dist >= 0 && dist < 256) ? S[nf][rr] : -1e30f;
          pm[nf][rr] = s;
          nmax[rr] = fmaxf(nmax[rr], s);
        }
      }
#pragma unroll
      for (int rr = 0; rr < 4; rr++) {
        float v = nmax[rr];
        v = fmaxf(v, __shfl_xor(v, 1, 64));
        v = fmaxf(v, __shfl_xor(v, 2, 64));
        v = fmaxf(v, __shfl_xor(v, 4, 64));
        v = fmaxf(v, __shfl_xor(v, 8, 64));
        const float mnew = fmaxf(mrow[rr], v);
        const float alpha = __expf(0.125f * (mrow[rr] - mnew));
        mrow[rr] = mnew;
        lrow[rr] *= alpha;
#pragma unroll
        for (int n = 0; n < 4; n++) O[n][rr] *= alpha;
        float ls = 0.f;
#pragma unroll
        for (int nf = 0; nf < 4; nf++) {
          const float s = pm[nf][rr];
          const float pv = (s < -1e29f) ? 0.f : __expf(0.125f * (s - mnew));
          pm[nf][rr] = pv;
          ls += pv;
        }
        ls += __shfl_xor(ls, 1, 64);
        ls += __shfl_xor(ls, 2, 64);
        ls += __shfl_xor(ls, 4, 64);
        ls += __shfl_xor(ls, 8, 64);
        lrow[rr] += ls;
      }
#pragma unroll
      for (int nf = 0; nf < 4; nf++)
#pragma unroll
        for (int rr = 0; rr < 4; rr++)
          Pl[w][g * 4 + rr][nf * 16 + r16] = f2bf(pm[nf][rr]);
#pragma unroll
      for (int kf = 0; kf < 2; kf++) {
        const short8 pa = *(const short8*)&Pl[w][r16][kf * 32 + g * 8];
#pragma unroll
        for (int n = 0; n < 4; n++) {
          const short8 vb8 = *(const short8*)&Vt[n * 16 + r16][kf * 32 + g * 8];
          O[n] = mfma16(pa, vb8, O[n]);
        }
      }
    }
    __syncthreads();
  }

#pragma unroll
  for (int n = 0; n < 4; n++) {
#pragma unroll
    for (int rr = 0; rr < 4; rr++) {
      const int t = qw + g * 4 + rr;
      const size_t idx = ((size_t)(b * 2048 + t)) * 1024 + h * 64 + n * 16 + r16;
      const float gv = bf2f(gate[idx]);
      const float ov = (O[n][rr] / lrow[rr]) * gv;
      out[idx] = f2bf(ov);
    }
  }
}

// ---------------------------------------------------------------------------
// Orchestration.
// ---------------------------------------------------------------------------
extern "C" void kernel_launch(void* const* d_in, const int* in_sizes, int n_in,
                              void* d_out, int out_size, void* d_ws,
                              size_t ws_size, hipStream_t stream) {
  (void)in_sizes; (void)n_in; (void)out_size; (void)ws_size;
  const float* x     = (const float*)d_in[0];
  const float* ln1   = (const float*)d_in[1];
  const float* qkvw  = (const float*)d_in[2];
  const float* gatew = (const float*)d_in[3];
  const float* outw  = (const float*)d_in[4];
  const float* ln2   = (const float*)d_in[5];
  const float* wg    = (const float*)d_in[6];
  const float* wu    = (const float*)d_in[7];
  const float* wo    = (const float*)d_in[8];
  float* outp = (float*)d_out;

  u16* p = (u16*)d_ws;
  u16* qkvw_b  = p; p += 3 * 1024 * 1024;   // adjacent to gatew_b (merged B)
  u16* gatew_b = p; p += 1024 * 1024;
  u16* outw_b  = p; p += 1024 * 1024;
  u16* wg_b    = p; p += 4 * 1024 * 1024;
  u16* wu_b    = p; p += 4 * 1024 * 1024;
  u16* wo_b    = p; p += 4 * 1024 * 1024;
  u16* xn      = p; p += 4096 * 1024;
  u16* qkvb    = p; p += (size_t)4096 * 3072;
  u16* gates   = p; p += 4096 * 1024;
  u16* a3      = p; p += 4096 * 1024;
  u16* hb      = p; p += 4096 * 1024;
  u16* gs      = p; p += (size_t)4096 * 4096;
  float* x2    = (float*)p;

  cvt_all_k<<<17408, 256, 0, stream>>>(qkvw, gatew, outw, wg, wu, wo,
                                       qkvw_b, gatew_b, outw_b, wg_b, wu_b, wo_b);

  rmsnorm_k<<<4096, 256, 0, stream>>>(x, ln1, xn);

  // merged qkv+gate: M=4096 N=4096 K=1024, 256^2 tiles, grid 16x16
  gemm8p<0, 6><<<dim3(16, 16), 512, 0, stream>>>(
      xn, qkvw_b, 4096, 1024, qkvb, nullptr, nullptr, nullptr, gates);

  attn_win_kernel<<<dim3(32, 16, 2), 256, 0, stream>>>(qkvb, gates, a3);

  // x2 = x + a3 @ out_w.T : M=4096 N=1024 K=1024, 128^2 tiles, grid 8x32
  gemm8p<1, 4><<<dim3(8, 32), 512, 0, stream>>>(
      a3, outw_b, 1024, 1024, nullptr, x2, nullptr, x, nullptr);

  rmsnorm_k<<<4096, 256, 0, stream>>>(x2, ln2, hb);

  // gs = silu(h @ wg.T); gs *= (h @ wu.T)
  gemm8p<0, 2><<<dim3(16, 16), 512, 0, stream>>>(
      hb, wg_b, 4096, 1024, gs, nullptr, nullptr, nullptr, nullptr);
  gemm8p<0, 3><<<dim3(16, 16), 512, 0, stream>>>(
      hb, wu_b, 4096, 1024, gs, nullptr, gs, nullptr, nullptr);

  // out = x2 + gs @ wo.T : M=4096 N=1024 K=4096, 128^2 tiles, grid 8x32
  gemm8p<1, 4><<<dim3(8, 32), 512, 0, stream>>>(
      gs, wo_b, 1024, 4096, nullptr, outp, nullptr, x2, nullptr);
}